// Round 9
// baseline (650.880 us; speedup 1.0000x reference)
//
#include <hip/hip_runtime.h>
#include <cstdint>
#include <cstddef>

#define B_   64
#define T_   256
#define DIN_ 128
#define H_   256
#define G3_  768   // 3*H

// ---------- helpers ----------
__device__ __forceinline__ unsigned short f2h(float f) {
  _Float16 h = (_Float16)f;              // v_cvt_f16_f32 (RNE)
  return __builtin_bit_cast(unsigned short, h);
}

// acc += dot(v2f16(a), v2f16(b)) in fp32
__device__ __forceinline__ void dot2f(float& acc, unsigned a, unsigned b) {
  asm("v_dot2_f32_f16 %0, %1, %2, %0" : "+v"(acc) : "v"(a), "v"(b));
}

// ---------- prep ----------
// Wreg layout for 512-thread gru: thread t: ks = t>>7, og = t&127.
// Thread owns outputs o = a*128+og (a in [0,6)) over k-slice [64*ks, 64*ks+64).
// w[j] (j = a*32 + qp, qp in [0,32) = k-pair): loaded as uint4 j4 = j>>2:
//   Wreg[(j4*512 + t)*4 + (j&3)] = f16pair(W_hh[o][64*ks+2*qp], [..+1])
// WheadT layout: [c][k]  (c in [0,96), k in [0,256))
__global__ __launch_bounds__(256) void prep_kernel(
    const float* __restrict__ W_ih, const float* __restrict__ W_hh,
    const float* __restrict__ W_mz, const float* __restrict__ W_mx,
    const float* __restrict__ W_pz, const float* __restrict__ W_cx,
    float* __restrict__ WT_ih, float* __restrict__ WheadT,
    unsigned* __restrict__ Wreg) {
  int i = blockIdx.x * 256 + threadIdx.x;
  if (i < 98304) {                       // WT_ih[k*768+g] = W_ih[g*128+k]
    int k = i / 768, g = i % 768;
    WT_ih[i] = W_ih[g * 128 + k];
  } else if (i < 98304 + 24576) {        // WheadT[c*256+k]
    int j = i - 98304;
    int c = j >> 8, k = j & 255;
    float v;
    if (c < 8)       v = W_mz[c * 256 + k];
    else if (c < 16) v = W_mx[(c - 8) * 256 + k];
    else if (c < 32) v = W_pz[(c - 16) * 256 + k];
    else             v = W_cx[(c - 32) * 256 + k];
    WheadT[j] = v;
  } else {                               // W_hh fp16-pair repack
    int m = i - 122880;                  // 0..98303
    int c = m & 3, n = m >> 2;
    int t = n & 511, j4 = n >> 9;        // j4 in [0,48)
    int j = 4 * j4 + c;                  // [0,192)
    int a = j >> 5, qp = j & 31;
    int o = a * 128 + (t & 127);
    int k0 = ((t >> 7) << 6) + 2 * qp;
    unsigned short lo = f2h(W_hh[o * 256 + k0]);
    unsigned short hi = f2h(W_hh[o * 256 + k0 + 1]);
    Wreg[m] = ((unsigned)hi << 16) | (unsigned)lo;
  }
}

// ---------- x_proj = y @ W_ih^T + b_ih : [16384,128]x[128,768] fp32 ----------
__global__ __launch_bounds__(256) void xproj_kernel(
    const float* __restrict__ y, const float* __restrict__ WT_ih,
    const float* __restrict__ b_ih, float* __restrict__ xp) {
  __shared__ float ylds[32][132];
  int tid = threadIdx.x;
  int row0 = blockIdx.x * 32;
  const float4* y4 = (const float4*)(y + (size_t)row0 * DIN_);
#pragma unroll
  for (int i = 0; i < 4; ++i) {
    int idx = i * 256 + tid;             // 1024 float4 = 32x128
    float4 v = y4[idx];
    int r = idx >> 5, c4 = (idx & 31) * 4;
    ylds[r][c4 + 0] = v.x; ylds[r][c4 + 1] = v.y;
    ylds[r][c4 + 2] = v.z; ylds[r][c4 + 3] = v.w;
  }
  __syncthreads();
  int tx = tid & 15, ty = tid >> 4;      // thread: 2 rows x 8 cols
  for (int c = 0; c < 6; ++c) {
    int col0 = c * 128 + tx * 8;
    float acc[2][8];
#pragma unroll
    for (int a = 0; a < 2; ++a)
#pragma unroll
      for (int b = 0; b < 8; ++b) acc[a][b] = 0.f;
#pragma unroll 4
    for (int k = 0; k < 128; ++k) {
      float4 w0 = *(const float4*)&WT_ih[k * 768 + col0];
      float4 w1 = *(const float4*)&WT_ih[k * 768 + col0 + 4];
      float a0 = ylds[ty * 2 + 0][k], a1 = ylds[ty * 2 + 1][k];
      acc[0][0] += a0 * w0.x; acc[0][1] += a0 * w0.y; acc[0][2] += a0 * w0.z; acc[0][3] += a0 * w0.w;
      acc[0][4] += a0 * w1.x; acc[0][5] += a0 * w1.y; acc[0][6] += a0 * w1.z; acc[0][7] += a0 * w1.w;
      acc[1][0] += a1 * w0.x; acc[1][1] += a1 * w0.y; acc[1][2] += a1 * w0.z; acc[1][3] += a1 * w0.w;
      acc[1][4] += a1 * w1.x; acc[1][5] += a1 * w1.y; acc[1][6] += a1 * w1.z; acc[1][7] += a1 * w1.w;
    }
    float4 b0 = *(const float4*)&b_ih[col0];
    float4 b1 = *(const float4*)&b_ih[col0 + 4];
#pragma unroll
    for (int a = 0; a < 2; ++a) {
      int row = row0 + ty * 2 + a;
      float4 o0, o1;
      o0.x = acc[a][0] + b0.x; o0.y = acc[a][1] + b0.y; o0.z = acc[a][2] + b0.z; o0.w = acc[a][3] + b0.w;
      o1.x = acc[a][4] + b1.x; o1.y = acc[a][5] + b1.y; o1.z = acc[a][6] + b1.z; o1.w = acc[a][7] + b1.w;
      *(float4*)&xp[(size_t)row * G3_ + col0] = o0;
      *(float4*)&xp[(size_t)row * G3_ + col0 + 4] = o1;
    }
  }
}

// ---------- GRU recurrence: 64 blocks x 512 threads ----------
// 8 waves = 2/SIMD -> 256-reg cap. Empty-asm "+v" pins w[192] in VGPRs every
// iteration: reload-from-global becomes illegal, so weights stay register-
// resident across the whole t-loop (round-8 counter showed the compiler was
// re-fetching Wreg from L2 every step; VGPR_Count 116 -> expect ~240 now).
__global__ __launch_bounds__(512, 2) void gru_kernel(
    const float* __restrict__ xp, const unsigned* __restrict__ Wreg,
    const float* __restrict__ b_hh, float* __restrict__ enc) {
  int tid = threadIdx.x;
  int ks = tid >> 7;                     // wave-uniform k-slice [64ks,64ks+64)
  int og = tid & 127;                    // outputs a*128+og
  int b = blockIdx.x;
  __shared__ alignas(16) unsigned short hsb[256];   // h state, fp16
  __shared__ alignas(16) float part[3104];          // 4 slices x 776 (pad 8)
  unsigned w[192];
  const uint4* W4 = (const uint4*)Wreg;
#pragma unroll
  for (int j4 = 0; j4 < 48; ++j4) {
    uint4 q = W4[j4 * 512 + tid];        // coalesced dwordx4
    w[4 * j4 + 0] = q.x; w[4 * j4 + 1] = q.y;
    w[4 * j4 + 2] = q.z; w[4 * j4 + 3] = q.w;
  }
  const float* xpb = xp + (size_t)b * (T_ * G3_);
  float* encb = enc + (size_t)b * (T_ * H_);
  float bhr = 0.f, bhz = 0.f, bhn = 0.f, hold = 0.f;
  float xr0 = 0.f, xz0 = 0.f, xn0 = 0.f, xr1 = 0.f, xz1 = 0.f, xn1 = 0.f;
  if (tid < 256) {
    bhr = b_hh[tid]; bhz = b_hh[256 + tid]; bhn = b_hh[512 + tid];
    xr0 = xpb[tid];        xz0 = xpb[256 + tid];        xn0 = xpb[512 + tid];
    xr1 = xpb[768 + tid];  xz1 = xpb[1024 + tid];       xn1 = xpb[1280 + tid];
    hsb[tid] = 0;                        // h0 = 0
  }
  __syncthreads();
  for (int t = 0; t < T_; ++t) {
#pragma unroll
    for (int j = 0; j < 192; ++j)
      asm volatile("" : "+v"(w[j]));     // pin: w must live in VGPRs here
    float xr2 = 0.f, xz2 = 0.f, xn2 = 0.f;
    if (tid < 256) {                     // prefetch t+2 (overrun lands in scratch)
      int base = (t + 2) * G3_ + tid;
      xr2 = xpb[base]; xz2 = xpb[base + 256]; xn2 = xpb[base + 512];
    }
    float p0 = 0.f, p1 = 0.f, p2 = 0.f, p3 = 0.f, p4 = 0.f, p5 = 0.f;
    const uint4* hs = ((const uint4*)hsb) + (ks << 3);   // 8 uint4 = 64 fp16
#pragma unroll
    for (int r = 0; r < 8; ++r) {
      uint4 hq = hs[r];                  // uniform addr -> LDS broadcast
      dot2f(p0, hq.x, w[(r << 2) + 0]);
      dot2f(p0, hq.y, w[(r << 2) + 1]);
      dot2f(p0, hq.z, w[(r << 2) + 2]);
      dot2f(p0, hq.w, w[(r << 2) + 3]);
      dot2f(p1, hq.x, w[32 + (r << 2) + 0]);
      dot2f(p1, hq.y, w[32 + (r << 2) + 1]);
      dot2f(p1, hq.z, w[32 + (r << 2) + 2]);
      dot2f(p1, hq.w, w[32 + (r << 2) + 3]);
      dot2f(p2, hq.x, w[64 + (r << 2) + 0]);
      dot2f(p2, hq.y, w[64 + (r << 2) + 1]);
      dot2f(p2, hq.z, w[64 + (r << 2) + 2]);
      dot2f(p2, hq.w, w[64 + (r << 2) + 3]);
      dot2f(p3, hq.x, w[96 + (r << 2) + 0]);
      dot2f(p3, hq.y, w[96 + (r << 2) + 1]);
      dot2f(p3, hq.z, w[96 + (r << 2) + 2]);
      dot2f(p3, hq.w, w[96 + (r << 2) + 3]);
      dot2f(p4, hq.x, w[128 + (r << 2) + 0]);
      dot2f(p4, hq.y, w[128 + (r << 2) + 1]);
      dot2f(p4, hq.z, w[128 + (r << 2) + 2]);
      dot2f(p4, hq.w, w[128 + (r << 2) + 3]);
      dot2f(p5, hq.x, w[160 + (r << 2) + 0]);
      dot2f(p5, hq.y, w[160 + (r << 2) + 1]);
      dot2f(p5, hq.z, w[160 + (r << 2) + 2]);
      dot2f(p5, hq.w, w[160 + (r << 2) + 3]);
    }
    int pb = ks * 776 + og;
    part[pb]       = p0;  part[pb + 128] = p1;
    part[pb + 256] = p2;  part[pb + 384] = p3;
    part[pb + 512] = p4;  part[pb + 640] = p5;
    __syncthreads();                     // partials visible; h reads done
    if (tid < 256) {
      int u = tid;
      float prer = bhr + ((part[u] + part[776 + u]) +
                          (part[1552 + u] + part[2328 + u]));
      float prez = bhz + ((part[256 + u] + part[1032 + u]) +
                          (part[1808 + u] + part[2584 + u]));
      float pren = bhn + ((part[512 + u] + part[1288 + u]) +
                          (part[2064 + u] + part[2840 + u]));
      float r_ = 1.f / (1.f + __expf(-(xr0 + prer)));
      float z_ = 1.f / (1.f + __expf(-(xz0 + prez)));
      float a = xn0 + r_ * pren;
      a = fminf(15.f, fmaxf(-15.f, a));
      float e = __expf(2.f * a);
      float n = (e - 1.f) / (e + 1.f);   // tanh
      float hnew = (1.f - z_) * n + z_ * hold;
      hold = hnew;                       // exact fp32 state in-register
      encb[t * H_ + u] = hnew;
      hsb[u] = f2h(hnew);
      xr0 = xr1; xz0 = xz1; xn0 = xn1;
      xr1 = xr2; xz1 = xz2; xn1 = xn2;
    }
    __syncthreads();                     // new h visible; part consumed
  }
}

// ---------- anchor[b][d] = enc[b,0,:] . W_mx[d] + b_mx[d],  d<2 ----------
__global__ void anchor_kernel(const float* __restrict__ enc,
                              const float* __restrict__ W_mx,
                              const float* __restrict__ b_mx,
                              float* __restrict__ anchor) {
  int tid = threadIdx.x;
  if (tid < 128) {
    int b = tid >> 1, d = tid & 1;
    const float* e = enc + (size_t)b * T_ * H_;    // t = 0 row
    float acc = b_mx[d];
    for (int k = 0; k < 256; ++k) acc += e[k] * W_mx[d * 256 + k];
    anchor[b * 2 + d] = acc;
  }
}

// ---------- heads: enc[16384,256] x WheadT[96,256]^T, k-vectorized ----------
__global__ __launch_bounds__(384) void heads_kernel(
    const float* __restrict__ enc, const float* __restrict__ WheadT,
    const float* __restrict__ b_mz, const float* __restrict__ b_mx,
    const float* __restrict__ b_pz, const float* __restrict__ b_cx,
    const float* __restrict__ anchor,
    float* __restrict__ out_meanz, float* __restrict__ out_meanx,
    float* __restrict__ out_covx, float* __restrict__ stage) {
  __shared__ float el[32 * 256];         // 32 KB
  int tid = threadIdx.x;
  int row0 = blockIdx.x * 32;
  const float4* e4 = (const float4*)(enc + (size_t)row0 * 256);
  float4* el4 = (float4*)el;
#pragma unroll
  for (int i = 0; i < 6; ++i) {
    int idx = i * 384 + tid;             // 2048 float4 = 32x64
    if (idx < 2048) el4[idx] = e4[idx];
  }
  __syncthreads();
  int rg = tid / 96, c = tid - rg * 96;  // rg in [0,4), c in [0,96)
  const float4* Wc = (const float4*)(WheadT + c * 256);
  float acc[8];
#pragma unroll
  for (int r = 0; r < 8; ++r) acc[r] = 0.f;
  for (int k4 = 0; k4 < 64; ++k4) {
    float4 w4 = Wc[k4];
#pragma unroll
    for (int r = 0; r < 8; ++r) {
      float4 ev = el4[(rg * 8 + r) * 64 + k4];
      acc[r] += w4.x * ev.x; acc[r] += w4.y * ev.y;
      acc[r] += w4.z * ev.z; acc[r] += w4.w * ev.w;
    }
  }
#pragma unroll
  for (int r = 0; r < 8; ++r) {
    int row = row0 + rg * 8 + r;
    int bb = row >> 8;
    float a_ = acc[r];
    if (c < 8) {
      out_meanz[(size_t)row * 8 + c] = a_ + b_mz[c];
    } else if (c < 16) {
      int d = c - 8;
      float v = a_ + b_mx[d];
      if (d < 2) v -= anchor[bb * 2 + d];
      out_meanx[(size_t)row * 8 + d] = v;
    } else if (c < 32) {
      int d = c - 16;
      float v = a_ + b_pz[d];
      if (d < 8)                          // diag: softplus (stable)
        v = (v > 0.f) ? (v + log1pf(__expf(-v))) : log1pf(__expf(v));
      stage[(size_t)row * 16 + d] = v;
    } else {
      int d = c - 32;
      out_covx[(size_t)row * 64 + d] = a_ + b_cx[d];
    }
  }
}

// ---------- fused zero + banded scatter: write chol in one pass ----------
__global__ __launch_bounds__(256) void chol_kernel(
    const float* __restrict__ stage, float4* __restrict__ chol) {
  int i = blockIdx.x * 256 + threadIdx.x;
  int stride = gridDim.x * 256;
  for (; i < 8388608; i += stride) {
    int d = i >> 20;                    // latent dim 0..7
    int bt = (i >> 6) & 16383;          // b*256 + t
    int t = bt & 255;
    int lane = i & 63;                  // float4 index within row
    float vd = 0.f, vo = 0.f;
    if ((t >> 2) == lane)        vd = stage[bt * 16 + d];       // diag col t
    if (((t + 1) >> 2) == lane)  vo = stage[bt * 16 + 8 + d];   // off col t+1
    int te = t & 3, oe = (t + 1) & 3;
    float4 v;
    v.x = (te == 0 ? vd : 0.f) + (oe == 0 ? vo : 0.f);
    v.y = (te == 1 ? vd : 0.f) + (oe == 1 ? vo : 0.f);
    v.z = (te == 2 ? vd : 0.f) + (oe == 2 ? vo : 0.f);
    v.w = (te == 3 ? vd : 0.f) + (oe == 3 ? vo : 0.f);
    chol[i] = v;
  }
}

extern "C" void kernel_launch(void* const* d_in, const int* in_sizes, int n_in,
                              void* d_out, int out_size, void* d_ws, size_t ws_size,
                              hipStream_t stream) {
  const float* y    = (const float*)d_in[0];
  const float* W_ih = (const float*)d_in[1];
  const float* W_hh = (const float*)d_in[2];
  const float* b_ih = (const float*)d_in[3];
  const float* b_hh = (const float*)d_in[4];
  const float* W_mz = (const float*)d_in[5];
  const float* b_mz = (const float*)d_in[6];
  const float* W_mx = (const float*)d_in[7];
  const float* b_mx = (const float*)d_in[8];
  const float* W_pz = (const float*)d_in[9];
  const float* b_pz = (const float*)d_in[10];
  const float* W_cx = (const float*)d_in[11];
  const float* b_cx = (const float*)d_in[12];

  float* out    = (float*)d_out;
  float* mean_z = out;                    // [64,256,8]
  float* chol   = out + 131072;           // [8,64,256,256]
  float* mean_x = out + 33685504;         // [16384,8]
  float* cov_x  = out + 33816576;         // [16384,8,8]

  float* ws      = (float*)d_ws;
  float* WT_ih   = ws;                    // 98304
  float* WheadT  = ws + 98304;            // 24576
  unsigned* Wreg = (unsigned*)(ws + 122880); // 98304
  float* anchor  = ws + 221184;           // 128
  float* stage   = ws + 221312;           // 262144

  // large scratch inside the chol output region (overwritten by chol_kernel)
  float* xp  = chol;                      // 12582912 floats
  float* enc = chol + 12582912;           // 4194304 floats

  prep_kernel<<<864, 256, 0, stream>>>(W_ih, W_hh, W_mz, W_mx, W_pz, W_cx,
                                       WT_ih, WheadT, Wreg);
  xproj_kernel<<<512, 256, 0, stream>>>(y, WT_ih, b_ih, xp);
  gru_kernel<<<64, 512, 0, stream>>>(xp, Wreg, b_hh, enc);
  anchor_kernel<<<1, 128, 0, stream>>>(enc, W_mx, b_mx, anchor);
  heads_kernel<<<512, 384, 0, stream>>>(enc, WheadT, b_mz, b_mx, b_pz, b_cx,
                                        anchor, mean_z, mean_x, cov_x, stage);
  chol_kernel<<<8192, 256, 0, stream>>>(stage, (float4*)chol);
}

// Round 10
// 642.491 us; speedup vs baseline: 1.0131x; 1.0131x over previous
//
#include <hip/hip_runtime.h>
#include <cstdint>
#include <cstddef>

#define B_   64
#define T_   256
#define DIN_ 128
#define H_   256
#define G3_  768   // 3*H

// ---------- helpers ----------
__device__ __forceinline__ unsigned short f2h(float f) {
  _Float16 h = (_Float16)f;              // v_cvt_f16_f32 (RNE)
  return __builtin_bit_cast(unsigned short, h);
}

// acc += dot(v2f16(a), v2f16(b)) in fp32
__device__ __forceinline__ void dot2f(float& acc, unsigned a, unsigned b) {
  asm("v_dot2_f32_f16 %0, %1, %2, %0" : "+v"(acc) : "v"(a), "v"(b));
}

// Pin 24 values into simultaneously-live VGPRs (emits nothing). Used ONCE
// before the t-loop: afterwards each w[j] is an asm output, so the compiler
// can no longer rematerialize it from Wreg inside the loop - it must carry
// all 192 in registers (fits: ~225 live < 256-reg cap at 2 waves/SIMD).
#define PIN24(p) asm volatile("" : \
  "+v"(p[0]),"+v"(p[1]),"+v"(p[2]),"+v"(p[3]),"+v"(p[4]),"+v"(p[5]), \
  "+v"(p[6]),"+v"(p[7]),"+v"(p[8]),"+v"(p[9]),"+v"(p[10]),"+v"(p[11]), \
  "+v"(p[12]),"+v"(p[13]),"+v"(p[14]),"+v"(p[15]),"+v"(p[16]),"+v"(p[17]), \
  "+v"(p[18]),"+v"(p[19]),"+v"(p[20]),"+v"(p[21]),"+v"(p[22]),"+v"(p[23]))

// ---------- prep ----------
// Wreg layout for 512-thread gru: thread t: ks = t>>7, og = t&127.
// Thread owns outputs o = a*128+og (a in [0,6)) over k-slice [64*ks, 64*ks+64).
// w[j] (j = a*32 + qp, qp in [0,32) = k-pair): loaded as uint4 j4 = j>>2:
//   Wreg[(j4*512 + t)*4 + (j&3)] = f16pair(W_hh[o][64*ks+2*qp], [..+1])
// WheadT layout: [c][k]  (c in [0,96), k in [0,256))
__global__ __launch_bounds__(256) void prep_kernel(
    const float* __restrict__ W_ih, const float* __restrict__ W_hh,
    const float* __restrict__ W_mz, const float* __restrict__ W_mx,
    const float* __restrict__ W_pz, const float* __restrict__ W_cx,
    float* __restrict__ WT_ih, float* __restrict__ WheadT,
    unsigned* __restrict__ Wreg) {
  int i = blockIdx.x * 256 + threadIdx.x;
  if (i < 98304) {                       // WT_ih[k*768+g] = W_ih[g*128+k]
    int k = i / 768, g = i % 768;
    WT_ih[i] = W_ih[g * 128 + k];
  } else if (i < 98304 + 24576) {        // WheadT[c*256+k]
    int j = i - 98304;
    int c = j >> 8, k = j & 255;
    float v;
    if (c < 8)       v = W_mz[c * 256 + k];
    else if (c < 16) v = W_mx[(c - 8) * 256 + k];
    else if (c < 32) v = W_pz[(c - 16) * 256 + k];
    else             v = W_cx[(c - 32) * 256 + k];
    WheadT[j] = v;
  } else {                               // W_hh fp16-pair repack
    int m = i - 122880;                  // 0..98303
    int c = m & 3, n = m >> 2;
    int t = n & 511, j4 = n >> 9;        // j4 in [0,48)
    int j = 4 * j4 + c;                  // [0,192)
    int a = j >> 5, qp = j & 31;
    int o = a * 128 + (t & 127);
    int k0 = ((t >> 7) << 6) + 2 * qp;
    unsigned short lo = f2h(W_hh[o * 256 + k0]);
    unsigned short hi = f2h(W_hh[o * 256 + k0 + 1]);
    Wreg[m] = ((unsigned)hi << 16) | (unsigned)lo;
  }
}

// ---------- x_proj = y @ W_ih^T + b_ih : [16384,128]x[128,768] fp32 ----------
__global__ __launch_bounds__(256) void xproj_kernel(
    const float* __restrict__ y, const float* __restrict__ WT_ih,
    const float* __restrict__ b_ih, float* __restrict__ xp) {
  __shared__ float ylds[32][132];
  int tid = threadIdx.x;
  int row0 = blockIdx.x * 32;
  const float4* y4 = (const float4*)(y + (size_t)row0 * DIN_);
#pragma unroll
  for (int i = 0; i < 4; ++i) {
    int idx = i * 256 + tid;             // 1024 float4 = 32x128
    float4 v = y4[idx];
    int r = idx >> 5, c4 = (idx & 31) * 4;
    ylds[r][c4 + 0] = v.x; ylds[r][c4 + 1] = v.y;
    ylds[r][c4 + 2] = v.z; ylds[r][c4 + 3] = v.w;
  }
  __syncthreads();
  int tx = tid & 15, ty = tid >> 4;      // thread: 2 rows x 8 cols
  for (int c = 0; c < 6; ++c) {
    int col0 = c * 128 + tx * 8;
    float acc[2][8];
#pragma unroll
    for (int a = 0; a < 2; ++a)
#pragma unroll
      for (int b = 0; b < 8; ++b) acc[a][b] = 0.f;
#pragma unroll 4
    for (int k = 0; k < 128; ++k) {
      float4 w0 = *(const float4*)&WT_ih[k * 768 + col0];
      float4 w1 = *(const float4*)&WT_ih[k * 768 + col0 + 4];
      float a0 = ylds[ty * 2 + 0][k], a1 = ylds[ty * 2 + 1][k];
      acc[0][0] += a0 * w0.x; acc[0][1] += a0 * w0.y; acc[0][2] += a0 * w0.z; acc[0][3] += a0 * w0.w;
      acc[0][4] += a0 * w1.x; acc[0][5] += a0 * w1.y; acc[0][6] += a0 * w1.z; acc[0][7] += a0 * w1.w;
      acc[1][0] += a1 * w0.x; acc[1][1] += a1 * w0.y; acc[1][2] += a1 * w0.z; acc[1][3] += a1 * w0.w;
      acc[1][4] += a1 * w1.x; acc[1][5] += a1 * w1.y; acc[1][6] += a1 * w1.z; acc[1][7] += a1 * w1.w;
    }
    float4 b0 = *(const float4*)&b_ih[col0];
    float4 b1 = *(const float4*)&b_ih[col0 + 4];
#pragma unroll
    for (int a = 0; a < 2; ++a) {
      int row = row0 + ty * 2 + a;
      float4 o0, o1;
      o0.x = acc[a][0] + b0.x; o0.y = acc[a][1] + b0.y; o0.z = acc[a][2] + b0.z; o0.w = acc[a][3] + b0.w;
      o1.x = acc[a][4] + b1.x; o1.y = acc[a][5] + b1.y; o1.z = acc[a][6] + b1.z; o1.w = acc[a][7] + b1.w;
      *(float4*)&xp[(size_t)row * G3_ + col0] = o0;
      *(float4*)&xp[(size_t)row * G3_ + col0 + 4] = o1;
    }
  }
}

// ---------- GRU recurrence: 64 blocks x 512 threads ----------
// 8 waves = 2/SIMD -> 256-reg cap. Single pre-loop pin (8 x 24-operand asm)
// makes w[192] asm outputs: in-loop rematerialization from Wreg is illegal,
// so weights stay VGPR-resident across all 256 steps.
__global__ __launch_bounds__(512, 2) void gru_kernel(
    const float* __restrict__ xp, const unsigned* __restrict__ Wreg,
    const float* __restrict__ b_hh, float* __restrict__ enc) {
  int tid = threadIdx.x;
  int ks = tid >> 7;                     // wave-uniform k-slice [64ks,64ks+64)
  int og = tid & 127;                    // outputs a*128+og
  int b = blockIdx.x;
  __shared__ alignas(16) unsigned short hsb[256];   // h state, fp16
  __shared__ alignas(16) float part[3104];          // 4 slices x 776 (pad 8)
  unsigned w[192];
  const uint4* W4 = (const uint4*)Wreg;
#pragma unroll
  for (int j4 = 0; j4 < 48; ++j4) {
    uint4 q = W4[j4 * 512 + tid];        // coalesced dwordx4
    w[4 * j4 + 0] = q.x; w[4 * j4 + 1] = q.y;
    w[4 * j4 + 2] = q.z; w[4 * j4 + 3] = q.w;
  }
  {                                      // ---- the pin: once, before t-loop
    unsigned* p = w;
    PIN24(p); p += 24; PIN24(p); p += 24; PIN24(p); p += 24; PIN24(p);
    p += 24;  PIN24(p); p += 24; PIN24(p); p += 24; PIN24(p); p += 24; PIN24(p);
  }
  const float* xpb = xp + (size_t)b * (T_ * G3_);
  float* encb = enc + (size_t)b * (T_ * H_);
  float bhr = 0.f, bhz = 0.f, bhn = 0.f, hold = 0.f;
  float xr0 = 0.f, xz0 = 0.f, xn0 = 0.f, xr1 = 0.f, xz1 = 0.f, xn1 = 0.f;
  if (tid < 256) {
    bhr = b_hh[tid]; bhz = b_hh[256 + tid]; bhn = b_hh[512 + tid];
    xr0 = xpb[tid];        xz0 = xpb[256 + tid];        xn0 = xpb[512 + tid];
    xr1 = xpb[768 + tid];  xz1 = xpb[1024 + tid];       xn1 = xpb[1280 + tid];
    hsb[tid] = 0;                        // h0 = 0
  }
  __syncthreads();
  for (int t = 0; t < T_; ++t) {
    float xr2 = 0.f, xz2 = 0.f, xn2 = 0.f;
    if (tid < 256) {                     // prefetch t+2 (overrun lands in scratch)
      int base = (t + 2) * G3_ + tid;
      xr2 = xpb[base]; xz2 = xpb[base + 256]; xn2 = xpb[base + 512];
    }
    float p0 = 0.f, p1 = 0.f, p2 = 0.f, p3 = 0.f, p4 = 0.f, p5 = 0.f;
    const uint4* hs = ((const uint4*)hsb) + (ks << 3);   // 8 uint4 = 64 fp16
#pragma unroll
    for (int r = 0; r < 8; ++r) {
      uint4 hq = hs[r];                  // uniform addr -> LDS broadcast
      dot2f(p0, hq.x, w[(r << 2) + 0]);
      dot2f(p0, hq.y, w[(r << 2) + 1]);
      dot2f(p0, hq.z, w[(r << 2) + 2]);
      dot2f(p0, hq.w, w[(r << 2) + 3]);
      dot2f(p1, hq.x, w[32 + (r << 2) + 0]);
      dot2f(p1, hq.y, w[32 + (r << 2) + 1]);
      dot2f(p1, hq.z, w[32 + (r << 2) + 2]);
      dot2f(p1, hq.w, w[32 + (r << 2) + 3]);
      dot2f(p2, hq.x, w[64 + (r << 2) + 0]);
      dot2f(p2, hq.y, w[64 + (r << 2) + 1]);
      dot2f(p2, hq.z, w[64 + (r << 2) + 2]);
      dot2f(p2, hq.w, w[64 + (r << 2) + 3]);
      dot2f(p3, hq.x, w[96 + (r << 2) + 0]);
      dot2f(p3, hq.y, w[96 + (r << 2) + 1]);
      dot2f(p3, hq.z, w[96 + (r << 2) + 2]);
      dot2f(p3, hq.w, w[96 + (r << 2) + 3]);
      dot2f(p4, hq.x, w[128 + (r << 2) + 0]);
      dot2f(p4, hq.y, w[128 + (r << 2) + 1]);
      dot2f(p4, hq.z, w[128 + (r << 2) + 2]);
      dot2f(p4, hq.w, w[128 + (r << 2) + 3]);
      dot2f(p5, hq.x, w[160 + (r << 2) + 0]);
      dot2f(p5, hq.y, w[160 + (r << 2) + 1]);
      dot2f(p5, hq.z, w[160 + (r << 2) + 2]);
      dot2f(p5, hq.w, w[160 + (r << 2) + 3]);
    }
    int pb = ks * 776 + og;
    part[pb]       = p0;  part[pb + 128] = p1;
    part[pb + 256] = p2;  part[pb + 384] = p3;
    part[pb + 512] = p4;  part[pb + 640] = p5;
    __syncthreads();                     // partials visible; h reads done
    if (tid < 256) {
      int u = tid;
      float prer = bhr + ((part[u] + part[776 + u]) +
                          (part[1552 + u] + part[2328 + u]));
      float prez = bhz + ((part[256 + u] + part[1032 + u]) +
                          (part[1808 + u] + part[2584 + u]));
      float pren = bhn + ((part[512 + u] + part[1288 + u]) +
                          (part[2064 + u] + part[2840 + u]));
      float r_ = 1.f / (1.f + __expf(-(xr0 + prer)));
      float z_ = 1.f / (1.f + __expf(-(xz0 + prez)));
      float a = xn0 + r_ * pren;
      a = fminf(15.f, fmaxf(-15.f, a));
      float e = __expf(2.f * a);
      float n = (e - 1.f) / (e + 1.f);   // tanh
      float hnew = (1.f - z_) * n + z_ * hold;
      hold = hnew;                       // exact fp32 state in-register
      encb[t * H_ + u] = hnew;
      hsb[u] = f2h(hnew);
      xr0 = xr1; xz0 = xz1; xn0 = xn1;
      xr1 = xr2; xz1 = xz2; xn1 = xn2;
    }
    __syncthreads();                     // new h visible; part consumed
  }
}

// ---------- anchor[b][d] = enc[b,0,:] . W_mx[d] + b_mx[d],  d<2 ----------
__global__ void anchor_kernel(const float* __restrict__ enc,
                              const float* __restrict__ W_mx,
                              const float* __restrict__ b_mx,
                              float* __restrict__ anchor) {
  int tid = threadIdx.x;
  if (tid < 128) {
    int b = tid >> 1, d = tid & 1;
    const float* e = enc + (size_t)b * T_ * H_;    // t = 0 row
    float acc = b_mx[d];
    for (int k = 0; k < 256; ++k) acc += e[k] * W_mx[d * 256 + k];
    anchor[b * 2 + d] = acc;
  }
}

// ---------- heads: enc[16384,256] x WheadT[96,256]^T, k-vectorized ----------
__global__ __launch_bounds__(384) void heads_kernel(
    const float* __restrict__ enc, const float* __restrict__ WheadT,
    const float* __restrict__ b_mz, const float* __restrict__ b_mx,
    const float* __restrict__ b_pz, const float* __restrict__ b_cx,
    const float* __restrict__ anchor,
    float* __restrict__ out_meanz, float* __restrict__ out_meanx,
    float* __restrict__ out_covx, float* __restrict__ stage) {
  __shared__ float el[32 * 256];         // 32 KB
  int tid = threadIdx.x;
  int row0 = blockIdx.x * 32;
  const float4* e4 = (const float4*)(enc + (size_t)row0 * 256);
  float4* el4 = (float4*)el;
#pragma unroll
  for (int i = 0; i < 6; ++i) {
    int idx = i * 384 + tid;             // 2048 float4 = 32x64
    if (idx < 2048) el4[idx] = e4[idx];
  }
  __syncthreads();
  int rg = tid / 96, c = tid - rg * 96;  // rg in [0,4), c in [0,96)
  const float4* Wc = (const float4*)(WheadT + c * 256);
  float acc[8];
#pragma unroll
  for (int r = 0; r < 8; ++r) acc[r] = 0.f;
  for (int k4 = 0; k4 < 64; ++k4) {
    float4 w4 = Wc[k4];
#pragma unroll
    for (int r = 0; r < 8; ++r) {
      float4 ev = el4[(rg * 8 + r) * 64 + k4];
      acc[r] += w4.x * ev.x; acc[r] += w4.y * ev.y;
      acc[r] += w4.z * ev.z; acc[r] += w4.w * ev.w;
    }
  }
#pragma unroll
  for (int r = 0; r < 8; ++r) {
    int row = row0 + rg * 8 + r;
    int bb = row >> 8;
    float a_ = acc[r];
    if (c < 8) {
      out_meanz[(size_t)row * 8 + c] = a_ + b_mz[c];
    } else if (c < 16) {
      int d = c - 8;
      float v = a_ + b_mx[d];
      if (d < 2) v -= anchor[bb * 2 + d];
      out_meanx[(size_t)row * 8 + d] = v;
    } else if (c < 32) {
      int d = c - 16;
      float v = a_ + b_pz[d];
      if (d < 8)                          // diag: softplus (stable)
        v = (v > 0.f) ? (v + log1pf(__expf(-v))) : log1pf(__expf(v));
      stage[(size_t)row * 16 + d] = v;
    } else {
      int d = c - 32;
      out_covx[(size_t)row * 64 + d] = a_ + b_cx[d];
    }
  }
}

// ---------- fused zero + banded scatter: write chol in one pass ----------
__global__ __launch_bounds__(256) void chol_kernel(
    const float* __restrict__ stage, float4* __restrict__ chol) {
  int i = blockIdx.x * 256 + threadIdx.x;
  int stride = gridDim.x * 256;
  for (; i < 8388608; i += stride) {
    int d = i >> 20;                    // latent dim 0..7
    int bt = (i >> 6) & 16383;          // b*256 + t
    int t = bt & 255;
    int lane = i & 63;                  // float4 index within row
    float vd = 0.f, vo = 0.f;
    if ((t >> 2) == lane)        vd = stage[bt * 16 + d];       // diag col t
    if (((t + 1) >> 2) == lane)  vo = stage[bt * 16 + 8 + d];   // off col t+1
    int te = t & 3, oe = (t + 1) & 3;
    float4 v;
    v.x = (te == 0 ? vd : 0.f) + (oe == 0 ? vo : 0.f);
    v.y = (te == 1 ? vd : 0.f) + (oe == 1 ? vo : 0.f);
    v.z = (te == 2 ? vd : 0.f) + (oe == 2 ? vo : 0.f);
    v.w = (te == 3 ? vd : 0.f) + (oe == 3 ? vo : 0.f);
    chol[i] = v;
  }
}

extern "C" void kernel_launch(void* const* d_in, const int* in_sizes, int n_in,
                              void* d_out, int out_size, void* d_ws, size_t ws_size,
                              hipStream_t stream) {
  const float* y    = (const float*)d_in[0];
  const float* W_ih = (const float*)d_in[1];
  const float* W_hh = (const float*)d_in[2];
  const float* b_ih = (const float*)d_in[3];
  const float* b_hh = (const float*)d_in[4];
  const float* W_mz = (const float*)d_in[5];
  const float* b_mz = (const float*)d_in[6];
  const float* W_mx = (const float*)d_in[7];
  const float* b_mx = (const float*)d_in[8];
  const float* W_pz = (const float*)d_in[9];
  const float* b_pz = (const float*)d_in[10];
  const float* W_cx = (const float*)d_in[11];
  const float* b_cx = (const float*)d_in[12];

  float* out    = (float*)d_out;
  float* mean_z = out;                    // [64,256,8]
  float* chol   = out + 131072;           // [8,64,256,256]
  float* mean_x = out + 33685504;         // [16384,8]
  float* cov_x  = out + 33816576;         // [16384,8,8]

  float* ws      = (float*)d_ws;
  float* WT_ih   = ws;                    // 98304
  float* WheadT  = ws + 98304;            // 24576
  unsigned* Wreg = (unsigned*)(ws + 122880); // 98304
  float* anchor  = ws + 221184;           // 128
  float* stage   = ws + 221312;           // 262144

  // large scratch inside the chol output region (overwritten by chol_kernel)
  float* xp  = chol;                      // 12582912 floats
  float* enc = chol + 12582912;           // 4194304 floats

  prep_kernel<<<864, 256, 0, stream>>>(W_ih, W_hh, W_mz, W_mx, W_pz, W_cx,
                                       WT_ih, WheadT, Wreg);
  xproj_kernel<<<512, 256, 0, stream>>>(y, WT_ih, b_ih, xp);
  gru_kernel<<<64, 512, 0, stream>>>(xp, Wreg, b_hh, enc);
  anchor_kernel<<<1, 128, 0, stream>>>(enc, W_mx, b_mx, anchor);
  heads_kernel<<<512, 384, 0, stream>>>(enc, WheadT, b_mz, b_mx, b_pz, b_cx,
                                        anchor, mean_z, mean_x, cov_x, stage);
  chol_kernel<<<8192, 256, 0, stream>>>(stage, (float4*)chol);
}

// Round 11
// 620.341 us; speedup vs baseline: 1.0492x; 1.0357x over previous
//
#include <hip/hip_runtime.h>
#include <cstdint>
#include <cstddef>

#define B_   64
#define T_   256
#define DIN_ 128
#define H_   256
#define G3_  768   // 3*H

// ---------- helpers ----------
__device__ __forceinline__ unsigned short f2h(float f) {
  _Float16 h = (_Float16)f;              // v_cvt_f16_f32 (RNE)
  return __builtin_bit_cast(unsigned short, h);
}

// acc += dot(v2f16(a), v2f16(b)) in fp32
__device__ __forceinline__ void dot2f(float& acc, unsigned a, unsigned b) {
  asm("v_dot2_f32_f16 %0, %1, %2, %0" : "+v"(acc) : "v"(a), "v"(b));
}

// ---------- prep ----------
// Wreg layout for 512-thread gru: thread t: ks = t>>7, og = t&127.
// Thread owns outputs o = a*128+og (a in [0,6)) over k-slice [64*ks, 64*ks+64).
// w[j] (j = a*32 + qp, qp in [0,32) = k-pair): loaded as uint4 j4 = j>>2:
//   Wreg[(j4*512 + t)*4 + (j&3)] = f16pair(W_hh[o][64*ks+2*qp], [..+1])
// WheadT layout: [c][k]  (c in [0,96), k in [0,256))
__global__ __launch_bounds__(256) void prep_kernel(
    const float* __restrict__ W_ih, const float* __restrict__ W_hh,
    const float* __restrict__ W_mz, const float* __restrict__ W_mx,
    const float* __restrict__ W_pz, const float* __restrict__ W_cx,
    float* __restrict__ WT_ih, float* __restrict__ WheadT,
    unsigned* __restrict__ Wreg) {
  int i = blockIdx.x * 256 + threadIdx.x;
  if (i < 98304) {                       // WT_ih[k*768+g] = W_ih[g*128+k]
    int k = i / 768, g = i % 768;
    WT_ih[i] = W_ih[g * 128 + k];
  } else if (i < 98304 + 24576) {        // WheadT[c*256+k]
    int j = i - 98304;
    int c = j >> 8, k = j & 255;
    float v;
    if (c < 8)       v = W_mz[c * 256 + k];
    else if (c < 16) v = W_mx[(c - 8) * 256 + k];
    else if (c < 32) v = W_pz[(c - 16) * 256 + k];
    else             v = W_cx[(c - 32) * 256 + k];
    WheadT[j] = v;
  } else {                               // W_hh fp16-pair repack
    int m = i - 122880;                  // 0..98303
    int c = m & 3, n = m >> 2;
    int t = n & 511, j4 = n >> 9;        // j4 in [0,48)
    int j = 4 * j4 + c;                  // [0,192)
    int a = j >> 5, qp = j & 31;
    int o = a * 128 + (t & 127);
    int k0 = ((t >> 7) << 6) + 2 * qp;
    unsigned short lo = f2h(W_hh[o * 256 + k0]);
    unsigned short hi = f2h(W_hh[o * 256 + k0 + 1]);
    Wreg[m] = ((unsigned)hi << 16) | (unsigned)lo;
  }
}

// ---------- x_proj = y @ W_ih^T + b_ih : [16384,128]x[128,768] fp32 ----------
__global__ __launch_bounds__(256) void xproj_kernel(
    const float* __restrict__ y, const float* __restrict__ WT_ih,
    const float* __restrict__ b_ih, float* __restrict__ xp) {
  __shared__ float ylds[32][132];
  int tid = threadIdx.x;
  int row0 = blockIdx.x * 32;
  const float4* y4 = (const float4*)(y + (size_t)row0 * DIN_);
#pragma unroll
  for (int i = 0; i < 4; ++i) {
    int idx = i * 256 + tid;             // 1024 float4 = 32x128
    float4 v = y4[idx];
    int r = idx >> 5, c4 = (idx & 31) * 4;
    ylds[r][c4 + 0] = v.x; ylds[r][c4 + 1] = v.y;
    ylds[r][c4 + 2] = v.z; ylds[r][c4 + 3] = v.w;
  }
  __syncthreads();
  int tx = tid & 15, ty = tid >> 4;      // thread: 2 rows x 8 cols
  for (int c = 0; c < 6; ++c) {
    int col0 = c * 128 + tx * 8;
    float acc[2][8];
#pragma unroll
    for (int a = 0; a < 2; ++a)
#pragma unroll
      for (int b = 0; b < 8; ++b) acc[a][b] = 0.f;
#pragma unroll 4
    for (int k = 0; k < 128; ++k) {
      float4 w0 = *(const float4*)&WT_ih[k * 768 + col0];
      float4 w1 = *(const float4*)&WT_ih[k * 768 + col0 + 4];
      float a0 = ylds[ty * 2 + 0][k], a1 = ylds[ty * 2 + 1][k];
      acc[0][0] += a0 * w0.x; acc[0][1] += a0 * w0.y; acc[0][2] += a0 * w0.z; acc[0][3] += a0 * w0.w;
      acc[0][4] += a0 * w1.x; acc[0][5] += a0 * w1.y; acc[0][6] += a0 * w1.z; acc[0][7] += a0 * w1.w;
      acc[1][0] += a1 * w0.x; acc[1][1] += a1 * w0.y; acc[1][2] += a1 * w0.z; acc[1][3] += a1 * w0.w;
      acc[1][4] += a1 * w1.x; acc[1][5] += a1 * w1.y; acc[1][6] += a1 * w1.z; acc[1][7] += a1 * w1.w;
    }
    float4 b0 = *(const float4*)&b_ih[col0];
    float4 b1 = *(const float4*)&b_ih[col0 + 4];
#pragma unroll
    for (int a = 0; a < 2; ++a) {
      int row = row0 + ty * 2 + a;
      float4 o0, o1;
      o0.x = acc[a][0] + b0.x; o0.y = acc[a][1] + b0.y; o0.z = acc[a][2] + b0.z; o0.w = acc[a][3] + b0.w;
      o1.x = acc[a][4] + b1.x; o1.y = acc[a][5] + b1.y; o1.z = acc[a][6] + b1.z; o1.w = acc[a][7] + b1.w;
      *(float4*)&xp[(size_t)row * G3_ + col0] = o0;
      *(float4*)&xp[(size_t)row * G3_ + col0 + 4] = o1;
    }
  }
}

// ---------- GRU recurrence: 64 blocks x 512 threads ----------
// The w[192] loads execute ONCE before the t-loop; an asm memory clobber at
// the top of every iteration makes re-loading (rematerialization) from Wreg
// illegal - the values must be carried in registers. amdgpu_waves_per_eu(2,2)
// grants the 256-reg/wave budget (~240 live fits, no spill).
__global__ __launch_bounds__(512) __attribute__((amdgpu_waves_per_eu(2, 2)))
void gru_kernel(
    const float* __restrict__ xp, const unsigned* Wreg,
    const float* __restrict__ b_hh, float* enc) {
  int tid = threadIdx.x;
  int ks = tid >> 7;                     // wave-uniform k-slice [64ks,64ks+64)
  int og = tid & 127;                    // outputs a*128+og
  int b = blockIdx.x;
  __shared__ alignas(16) unsigned short hsb[256];   // h state, fp16
  __shared__ alignas(16) float part[3104];          // 4 slices x 776 (pad 8)
  unsigned w[192];
  const uint4* W4 = (const uint4*)Wreg;
#pragma unroll
  for (int j4 = 0; j4 < 48; ++j4) {
    uint4 q = W4[j4 * 512 + tid];        // coalesced dwordx4, once
    w[4 * j4 + 0] = q.x; w[4 * j4 + 1] = q.y;
    w[4 * j4 + 2] = q.z; w[4 * j4 + 3] = q.w;
  }
  const float* xpb = xp + (size_t)b * (T_ * G3_);
  float* encb = enc + (size_t)b * (T_ * H_);
  float bhr = 0.f, bhz = 0.f, bhn = 0.f, hold = 0.f;
  float xr0 = 0.f, xz0 = 0.f, xn0 = 0.f, xr1 = 0.f, xz1 = 0.f, xn1 = 0.f;
  if (tid < 256) {
    bhr = b_hh[tid]; bhz = b_hh[256 + tid]; bhn = b_hh[512 + tid];
    xr0 = xpb[tid];        xz0 = xpb[256 + tid];        xn0 = xpb[512 + tid];
    xr1 = xpb[768 + tid];  xz1 = xpb[1024 + tid];       xn1 = xpb[1280 + tid];
    hsb[tid] = 0;                        // h0 = 0
  }
  __syncthreads();
  for (int t = 0; t < T_; ++t) {
    asm volatile("" ::: "memory");       // all memory may have changed:
                                         // reloading w from Wreg is illegal
    float xr2 = 0.f, xz2 = 0.f, xn2 = 0.f;
    if (tid < 256) {                     // prefetch t+2 (overrun lands in scratch)
      int base = (t + 2) * G3_ + tid;
      xr2 = xpb[base]; xz2 = xpb[base + 256]; xn2 = xpb[base + 512];
    }
    float p0 = 0.f, p1 = 0.f, p2 = 0.f, p3 = 0.f, p4 = 0.f, p5 = 0.f;
    const uint4* hs = ((const uint4*)hsb) + (ks << 3);   // 8 uint4 = 64 fp16
#pragma unroll
    for (int r = 0; r < 8; ++r) {
      uint4 hq = hs[r];                  // uniform addr -> LDS broadcast
      dot2f(p0, hq.x, w[(r << 2) + 0]);
      dot2f(p0, hq.y, w[(r << 2) + 1]);
      dot2f(p0, hq.z, w[(r << 2) + 2]);
      dot2f(p0, hq.w, w[(r << 2) + 3]);
      dot2f(p1, hq.x, w[32 + (r << 2) + 0]);
      dot2f(p1, hq.y, w[32 + (r << 2) + 1]);
      dot2f(p1, hq.z, w[32 + (r << 2) + 2]);
      dot2f(p1, hq.w, w[32 + (r << 2) + 3]);
      dot2f(p2, hq.x, w[64 + (r << 2) + 0]);
      dot2f(p2, hq.y, w[64 + (r << 2) + 1]);
      dot2f(p2, hq.z, w[64 + (r << 2) + 2]);
      dot2f(p2, hq.w, w[64 + (r << 2) + 3]);
      dot2f(p3, hq.x, w[96 + (r << 2) + 0]);
      dot2f(p3, hq.y, w[96 + (r << 2) + 1]);
      dot2f(p3, hq.z, w[96 + (r << 2) + 2]);
      dot2f(p3, hq.w, w[96 + (r << 2) + 3]);
      dot2f(p4, hq.x, w[128 + (r << 2) + 0]);
      dot2f(p4, hq.y, w[128 + (r << 2) + 1]);
      dot2f(p4, hq.z, w[128 + (r << 2) + 2]);
      dot2f(p4, hq.w, w[128 + (r << 2) + 3]);
      dot2f(p5, hq.x, w[160 + (r << 2) + 0]);
      dot2f(p5, hq.y, w[160 + (r << 2) + 1]);
      dot2f(p5, hq.z, w[160 + (r << 2) + 2]);
      dot2f(p5, hq.w, w[160 + (r << 2) + 3]);
    }
    int pb = ks * 776 + og;
    part[pb]       = p0;  part[pb + 128] = p1;
    part[pb + 256] = p2;  part[pb + 384] = p3;
    part[pb + 512] = p4;  part[pb + 640] = p5;
    __syncthreads();                     // partials visible; h reads done
    if (tid < 256) {
      int u = tid;
      float prer = bhr + ((part[u] + part[776 + u]) +
                          (part[1552 + u] + part[2328 + u]));
      float prez = bhz + ((part[256 + u] + part[1032 + u]) +
                          (part[1808 + u] + part[2584 + u]));
      float pren = bhn + ((part[512 + u] + part[1288 + u]) +
                          (part[2064 + u] + part[2840 + u]));
      float r_ = 1.f / (1.f + __expf(-(xr0 + prer)));
      float z_ = 1.f / (1.f + __expf(-(xz0 + prez)));
      float a = xn0 + r_ * pren;
      a = fminf(15.f, fmaxf(-15.f, a));
      float e = __expf(2.f * a);
      float n = (e - 1.f) / (e + 1.f);   // tanh
      float hnew = (1.f - z_) * n + z_ * hold;
      hold = hnew;                       // exact fp32 state in-register
      encb[t * H_ + u] = hnew;
      hsb[u] = f2h(hnew);
      xr0 = xr1; xz0 = xz1; xn0 = xn1;
      xr1 = xr2; xz1 = xz2; xn1 = xn2;
    }
    __syncthreads();                     // new h visible; part consumed
  }
}

// ---------- anchor[b][d] = enc[b,0,:] . W_mx[d] + b_mx[d],  d<2 ----------
__global__ void anchor_kernel(const float* __restrict__ enc,
                              const float* __restrict__ W_mx,
                              const float* __restrict__ b_mx,
                              float* __restrict__ anchor) {
  int tid = threadIdx.x;
  if (tid < 128) {
    int b = tid >> 1, d = tid & 1;
    const float* e = enc + (size_t)b * T_ * H_;    // t = 0 row
    float acc = b_mx[d];
    for (int k = 0; k < 256; ++k) acc += e[k] * W_mx[d * 256 + k];
    anchor[b * 2 + d] = acc;
  }
}

// ---------- heads: enc[16384,256] x WheadT[96,256]^T, k-vectorized ----------
__global__ __launch_bounds__(384) void heads_kernel(
    const float* __restrict__ enc, const float* __restrict__ WheadT,
    const float* __restrict__ b_mz, const float* __restrict__ b_mx,
    const float* __restrict__ b_pz, const float* __restrict__ b_cx,
    const float* __restrict__ anchor,
    float* __restrict__ out_meanz, float* __restrict__ out_meanx,
    float* __restrict__ out_covx, float* __restrict__ stage) {
  __shared__ float el[32 * 256];         // 32 KB
  int tid = threadIdx.x;
  int row0 = blockIdx.x * 32;
  const float4* e4 = (const float4*)(enc + (size_t)row0 * 256);
  float4* el4 = (float4*)el;
#pragma unroll
  for (int i = 0; i < 6; ++i) {
    int idx = i * 384 + tid;             // 2048 float4 = 32x64
    if (idx < 2048) el4[idx] = e4[idx];
  }
  __syncthreads();
  int rg = tid / 96, c = tid - rg * 96;  // rg in [0,4), c in [0,96)
  const float4* Wc = (const float4*)(WheadT + c * 256);
  float acc[8];
#pragma unroll
  for (int r = 0; r < 8; ++r) acc[r] = 0.f;
  for (int k4 = 0; k4 < 64; ++k4) {
    float4 w4 = Wc[k4];
#pragma unroll
    for (int r = 0; r < 8; ++r) {
      float4 ev = el4[(rg * 8 + r) * 64 + k4];
      acc[r] += w4.x * ev.x; acc[r] += w4.y * ev.y;
      acc[r] += w4.z * ev.z; acc[r] += w4.w * ev.w;
    }
  }
#pragma unroll
  for (int r = 0; r < 8; ++r) {
    int row = row0 + rg * 8 + r;
    int bb = row >> 8;
    float a_ = acc[r];
    if (c < 8) {
      out_meanz[(size_t)row * 8 + c] = a_ + b_mz[c];
    } else if (c < 16) {
      int d = c - 8;
      float v = a_ + b_mx[d];
      if (d < 2) v -= anchor[bb * 2 + d];
      out_meanx[(size_t)row * 8 + d] = v;
    } else if (c < 32) {
      int d = c - 16;
      float v = a_ + b_pz[d];
      if (d < 8)                          // diag: softplus (stable)
        v = (v > 0.f) ? (v + log1pf(__expf(-v))) : log1pf(__expf(v));
      stage[(size_t)row * 16 + d] = v;
    } else {
      int d = c - 32;
      out_covx[(size_t)row * 64 + d] = a_ + b_cx[d];
    }
  }
}

// ---------- fused zero + banded scatter: write chol in one pass ----------
__global__ __launch_bounds__(256) void chol_kernel(
    const float* __restrict__ stage, float4* __restrict__ chol) {
  int i = blockIdx.x * 256 + threadIdx.x;
  int stride = gridDim.x * 256;
  for (; i < 8388608; i += stride) {
    int d = i >> 20;                    // latent dim 0..7
    int bt = (i >> 6) & 16383;          // b*256 + t
    int t = bt & 255;
    int lane = i & 63;                  // float4 index within row
    float vd = 0.f, vo = 0.f;
    if ((t >> 2) == lane)        vd = stage[bt * 16 + d];       // diag col t
    if (((t + 1) >> 2) == lane)  vo = stage[bt * 16 + 8 + d];   // off col t+1
    int te = t & 3, oe = (t + 1) & 3;
    float4 v;
    v.x = (te == 0 ? vd : 0.f) + (oe == 0 ? vo : 0.f);
    v.y = (te == 1 ? vd : 0.f) + (oe == 1 ? vo : 0.f);
    v.z = (te == 2 ? vd : 0.f) + (oe == 2 ? vo : 0.f);
    v.w = (te == 3 ? vd : 0.f) + (oe == 3 ? vo : 0.f);
    chol[i] = v;
  }
}

extern "C" void kernel_launch(void* const* d_in, const int* in_sizes, int n_in,
                              void* d_out, int out_size, void* d_ws, size_t ws_size,
                              hipStream_t stream) {
  const float* y    = (const float*)d_in[0];
  const float* W_ih = (const float*)d_in[1];
  const float* W_hh = (const float*)d_in[2];
  const float* b_ih = (const float*)d_in[3];
  const float* b_hh = (const float*)d_in[4];
  const float* W_mz = (const float*)d_in[5];
  const float* b_mz = (const float*)d_in[6];
  const float* W_mx = (const float*)d_in[7];
  const float* b_mx = (const float*)d_in[8];
  const float* W_pz = (const float*)d_in[9];
  const float* b_pz = (const float*)d_in[10];
  const float* W_cx = (const float*)d_in[11];
  const float* b_cx = (const float*)d_in[12];

  float* out    = (float*)d_out;
  float* mean_z = out;                    // [64,256,8]
  float* chol   = out + 131072;           // [8,64,256,256]
  float* mean_x = out + 33685504;         // [16384,8]
  float* cov_x  = out + 33816576;         // [16384,8,8]

  float* ws      = (float*)d_ws;
  float* WT_ih   = ws;                    // 98304
  float* WheadT  = ws + 98304;            // 24576
  unsigned* Wreg = (unsigned*)(ws + 122880); // 98304
  float* anchor  = ws + 221184;           // 128
  float* stage   = ws + 221312;           // 262144

  // large scratch inside the chol output region (overwritten by chol_kernel)
  float* xp  = chol;                      // 12582912 floats
  float* enc = chol + 12582912;           // 4194304 floats

  prep_kernel<<<864, 256, 0, stream>>>(W_ih, W_hh, W_mz, W_mx, W_pz, W_cx,
                                       WT_ih, WheadT, Wreg);
  xproj_kernel<<<512, 256, 0, stream>>>(y, WT_ih, b_ih, xp);
  gru_kernel<<<64, 512, 0, stream>>>(xp, Wreg, b_hh, enc);
  anchor_kernel<<<1, 128, 0, stream>>>(enc, W_mx, b_mx, anchor);
  heads_kernel<<<512, 384, 0, stream>>>(enc, WheadT, b_mz, b_mx, b_pz, b_cx,
                                        anchor, mean_z, mean_x, cov_x, stage);
  chol_kernel<<<8192, 256, 0, stream>>>(stage, (float4*)chol);
}